// Round 1
// baseline (5638.538 us; speedup 1.0000x reference)
//
#include <hip/hip_runtime.h>

#define NN 100000
#define NE 1600000
#define FD 128
#define NG 64
#define OUTD 64

static __device__ __forceinline__ void atomAdd(float* p, float v) {
    __hip_atomic_fetch_add(p, v, __ATOMIC_RELAXED, __HIP_MEMORY_SCOPE_AGENT);
}

// ---- degree: deg[v] = # incoming edges ----
__global__ void k_deg(const int* __restrict__ dst, float* __restrict__ deg) {
    int i = blockIdx.x * blockDim.x + threadIdx.x;
    if (i < NE) atomAdd(&deg[dst[i]], 1.0f);
}

// ---- per-graph node counts (graph_ids sorted; LDS pre-reduce) ----
__global__ void k_gcount(const int* __restrict__ gid, float* __restrict__ gcount) {
    __shared__ float c[NG];
    if (threadIdx.x < NG) c[threadIdx.x] = 0.0f;
    __syncthreads();
    int i = blockIdx.x * blockDim.x + threadIdx.x;
    if (i < NN) atomicAdd(&c[gid[i]], 1.0f);
    __syncthreads();
    if (threadIdx.x < NG) {
        float v = c[threadIdx.x];
        if (v != 0.0f) atomAdd(&gcount[threadIdx.x], v);
    }
}

// ---- edge scatter: agg[dst] += x[src]; 32 threads (8 float4) per edge ----
__global__ void k_scatter(const float* __restrict__ x, const int* __restrict__ src,
                          const int* __restrict__ dst, float* __restrict__ agg) {
    long long tid = (long long)blockIdx.x * blockDim.x + threadIdx.x;
    int e = (int)(tid >> 5);
    if (e >= NE) return;
    int f = ((int)tid & 31) << 2;
    int s = src[e], d = dst[e];
    float4 v = *reinterpret_cast<const float4*>(x + (size_t)s * FD + f);
    float* o = agg + (size_t)d * FD + f;
    atomAdd(o + 0, v.x);
    atomAdd(o + 1, v.y);
    atomAdd(o + 2, v.z);
    atomAdd(o + 3, v.w);
}

// ---- GIN node update: h = relu((x + agg/max(deg,1)) @ W + b) ----
// 32 nodes per block, W (64KB) + input tile (16KB) in LDS, 4x4 register tile.
// FUSE_HG: skip writing h; accumulate per-graph sums into hg_sum (graph_ids sorted).
template <bool FUSE_HG>
__global__ __launch_bounds__(256, 2) void k_node(
    const float* __restrict__ xin, const float* __restrict__ agg,
    const float* __restrict__ deg, const float* __restrict__ W,
    const float* __restrict__ b, float* __restrict__ hout,
    const int* __restrict__ gid, float* __restrict__ hg_sum)
{
    __shared__ float Wl[FD * FD];   // 64 KB
    __shared__ float T[32 * FD];    // 16 KB
    const int tid = threadIdx.x;
    const int base = blockIdx.x * 32;

    // load W into LDS (4096 float4, 16 per thread)
    {
        const float4* Wv = reinterpret_cast<const float4*>(W);
        float4* Wlv = reinterpret_cast<float4*>(Wl);
        #pragma unroll
        for (int i = 0; i < 16; ++i)
            Wlv[i * 256 + tid] = Wv[i * 256 + tid];
    }
    // stage t = x + agg * 1/max(deg,1) for 32 nodes (1024 float4, 4 per thread)
    {
        const float4* xv4 = reinterpret_cast<const float4*>(xin);
        const float4* av4 = reinterpret_cast<const float4*>(agg);
        float4* Tv = reinterpret_cast<float4*>(T);
        #pragma unroll
        for (int i = 0; i < 4; ++i) {
            int idx = i * 256 + tid;          // 0..1023
            int n = idx >> 5;                 // node within block (32 f4 each)
            int node = base + n;
            float inv = 1.0f / fmaxf(deg[node], 1.0f);
            float4 xv = xv4[(size_t)node * 32 + (idx & 31)];
            float4 av = av4[(size_t)node * 32 + (idx & 31)];
            float4 t;
            t.x = xv.x + av.x * inv;
            t.y = xv.y + av.y * inv;
            t.z = xv.z + av.z * inv;
            t.w = xv.w + av.w * inv;
            Tv[idx] = t;
        }
    }
    __syncthreads();

    // thread -> 4 features x 4 nodes
    const int fg = tid & 31;        // feature quad
    const int ng = tid >> 5;        // node group 0..7
    const int f0 = fg * 4;
    const int n0 = ng * 4;

    float4 bv = *reinterpret_cast<const float4*>(b + f0);
    float acc[4][4];
    #pragma unroll
    for (int n = 0; n < 4; ++n) {
        acc[n][0] = bv.x; acc[n][1] = bv.y; acc[n][2] = bv.z; acc[n][3] = bv.w;
    }

    #pragma unroll 4
    for (int k = 0; k < FD; k += 4) {
        float4 w0 = *reinterpret_cast<const float4*>(&Wl[(k + 0) * FD + f0]);
        float4 w1 = *reinterpret_cast<const float4*>(&Wl[(k + 1) * FD + f0]);
        float4 w2 = *reinterpret_cast<const float4*>(&Wl[(k + 2) * FD + f0]);
        float4 w3 = *reinterpret_cast<const float4*>(&Wl[(k + 3) * FD + f0]);
        #pragma unroll
        for (int n = 0; n < 4; ++n) {
            float4 tv = *reinterpret_cast<const float4*>(&T[(n0 + n) * FD + k]);
            acc[n][0] += tv.x * w0.x + tv.y * w1.x + tv.z * w2.x + tv.w * w3.x;
            acc[n][1] += tv.x * w0.y + tv.y * w1.y + tv.z * w2.y + tv.w * w3.y;
            acc[n][2] += tv.x * w0.z + tv.y * w1.z + tv.z * w2.z + tv.w * w3.z;
            acc[n][3] += tv.x * w0.w + tv.y * w1.w + tv.z * w2.w + tv.w * w3.w;
        }
    }

    if (!FUSE_HG) {
        #pragma unroll
        for (int n = 0; n < 4; ++n) {
            float4 o;
            o.x = fmaxf(acc[n][0], 0.0f);
            o.y = fmaxf(acc[n][1], 0.0f);
            o.z = fmaxf(acc[n][2], 0.0f);
            o.w = fmaxf(acc[n][3], 0.0f);
            *reinterpret_cast<float4*>(hout + (size_t)(base + n0 + n) * FD + f0) = o;
        }
    } else {
        int curg = gid[base + n0];
        float r0 = 0.f, r1 = 0.f, r2 = 0.f, r3 = 0.f;
        #pragma unroll
        for (int n = 0; n < 4; ++n) {
            int g = gid[base + n0 + n];
            if (g != curg) {
                float* hp = hg_sum + (size_t)curg * FD + f0;
                atomAdd(hp + 0, r0); atomAdd(hp + 1, r1);
                atomAdd(hp + 2, r2); atomAdd(hp + 3, r3);
                r0 = r1 = r2 = r3 = 0.f;
                curg = g;
            }
            r0 += fmaxf(acc[n][0], 0.0f);
            r1 += fmaxf(acc[n][1], 0.0f);
            r2 += fmaxf(acc[n][2], 0.0f);
            r3 += fmaxf(acc[n][3], 0.0f);
        }
        float* hp = hg_sum + (size_t)curg * FD + f0;
        atomAdd(hp + 0, r0); atomAdd(hp + 1, r1);
        atomAdd(hp + 2, r2); atomAdd(hp + 3, r3);
    }
}

// ---- hg = hg_sum / max(count,1) -> d_out[0:8192] ----
__global__ void k_hg(const float* __restrict__ hg_sum, const float* __restrict__ gcount,
                     float* __restrict__ out) {
    int i = blockIdx.x * blockDim.x + threadIdx.x;   // 0..8191
    int g = i >> 7;
    out[i] = hg_sum[i] / fmaxf(gcount[g], 1.0f);
}

// ---- t1 = relu(hg @ Wd1 + bd1) ----
__global__ void k_rec1(const float* __restrict__ hg, const float* __restrict__ Wd1,
                       const float* __restrict__ bd1, float* __restrict__ t1) {
    int i = blockIdx.x * blockDim.x + threadIdx.x;   // 0..8191
    int n = i >> 7, f = i & 127;
    float acc = bd1[f];
    #pragma unroll 8
    for (int k = 0; k < FD; ++k)
        acc += hg[n * FD + k] * Wd1[k * FD + f];
    t1[i] = fmaxf(acc, 0.0f);
}

// ---- rec = t1 @ Wd2 + bd2 -> d_out[8192:12288] ----
__global__ void k_rec2(const float* __restrict__ t1, const float* __restrict__ Wd2,
                       const float* __restrict__ bd2, float* __restrict__ out) {
    int i = blockIdx.x * blockDim.x + threadIdx.x;   // 0..4095
    int n = i >> 6, f = i & 63;
    float acc = bd2[f];
    #pragma unroll 8
    for (int k = 0; k < FD; ++k)
        acc += t1[n * FD + k] * Wd2[k * OUTD + f];
    out[i] = acc;
}

extern "C" void kernel_launch(void* const* d_in, const int* in_sizes, int n_in,
                              void* d_out, int out_size, void* d_ws, size_t ws_size,
                              hipStream_t stream) {
    const float* feat = (const float*)d_in[0];
    const int*   src  = (const int*)d_in[1];
    const int*   dst  = (const int*)d_in[2];
    const int*   gid  = (const int*)d_in[3];
    const float* W1   = (const float*)d_in[4];
    const float* b1   = (const float*)d_in[5];
    const float* W2   = (const float*)d_in[6];
    const float* b2   = (const float*)d_in[7];
    const float* Wd1  = (const float*)d_in[8];
    const float* bd1  = (const float*)d_in[9];
    const float* Wd2  = (const float*)d_in[10];
    const float* bd2  = (const float*)d_in[11];
    float* out = (float*)d_out;

    float* ws = (float*)d_ws;
    float* deg    = ws;                          // 100000
    float* gcount = ws + 100000;                 // 64
    float* hg_sum = ws + 100064;                 // 8192
    float* agg    = ws + 108256;                 // 12,800,000
    float* h1     = ws + 12908256;               // 12,800,000
    float* t1     = ws + 25708256;               // 8192

    // zero deg + gcount + hg_sum + agg in one contiguous memset
    hipMemsetAsync(ws, 0, (size_t)12908256 * 4, stream);

    k_deg<<<(NE + 255) / 256, 256, 0, stream>>>(dst, deg);
    k_gcount<<<(NN + 255) / 256, 256, 0, stream>>>(gid, gcount);

    // layer 1
    k_scatter<<<200000, 256, 0, stream>>>(feat, src, dst, agg);
    k_node<false><<<NN / 32, 256, 0, stream>>>(feat, agg, deg, W1, b1, h1, nullptr, nullptr);

    // layer 2
    hipMemsetAsync(agg, 0, (size_t)12800000 * 4, stream);
    k_scatter<<<200000, 256, 0, stream>>>(h1, src, dst, agg);
    k_node<true><<<NN / 32, 256, 0, stream>>>(h1, agg, deg, W2, b2, nullptr, gid, hg_sum);

    // pool + decoder
    k_hg<<<32, 256, 0, stream>>>(hg_sum, gcount, out);
    k_rec1<<<32, 256, 0, stream>>>(out, Wd1, bd1, t1);
    k_rec2<<<16, 256, 0, stream>>>(t1, Wd2, bd2, out + 8192);
}

// Round 2
// 889.684 us; speedup vs baseline: 6.3377x; 6.3377x over previous
//
#include <hip/hip_runtime.h>

#define NN 100000
#define NE 1600000
#define FD 128
#define NG 64
#define OUTD 64
#define NBLK 391   // ceil(NN/256)

static __device__ __forceinline__ void atomAddF(float* p, float v) {
    __hip_atomic_fetch_add(p, v, __ATOMIC_RELAXED, __HIP_MEMORY_SCOPE_AGENT);
}
static __device__ __forceinline__ int atomAddI(int* p, int v) {
    return __hip_atomic_fetch_add(p, v, __ATOMIC_RELAXED, __HIP_MEMORY_SCOPE_AGENT);
}
static __device__ __forceinline__ void add4(float4& a, const float4 b) {
    a.x += b.x; a.y += b.y; a.z += b.z; a.w += b.w;
}
static __device__ __forceinline__ float4 axpy4(const float4 a, float s, const float4 x) {
    float4 r;
    r.x = x.x + a.x * s; r.y = x.y + a.y * s;
    r.z = x.z + a.z * s; r.w = x.w + a.w * s;
    return r;
}

// ---- int degree histogram over dst ----
__global__ void k_hist(const int* __restrict__ dst, int* __restrict__ degi) {
    int i = blockIdx.x * blockDim.x + threadIdx.x;
    if (i < NE) atomAddI(&degi[dst[i]], 1);
}

// ---- per-graph node counts (graph_ids sorted; LDS pre-reduce) ----
__global__ void k_gcount(const int* __restrict__ gid, float* __restrict__ gcount) {
    __shared__ float c[NG];
    if (threadIdx.x < NG) c[threadIdx.x] = 0.0f;
    __syncthreads();
    int i = blockIdx.x * blockDim.x + threadIdx.x;
    if (i < NN) atomicAdd(&c[gid[i]], 1.0f);
    __syncthreads();
    if (threadIdx.x < NG) {
        float v = c[threadIdx.x];
        if (v != 0.0f) atomAddF(&gcount[threadIdx.x], v);
    }
}

// ---- scan step 1: per-block sums of degi ----
__global__ void k_scan1(const int* __restrict__ degi, int* __restrict__ bsum) {
    __shared__ int s[256];
    int i = blockIdx.x * 256 + threadIdx.x;
    s[threadIdx.x] = (i < NN) ? degi[i] : 0;
    __syncthreads();
    for (int d = 128; d > 0; d >>= 1) {
        if (threadIdx.x < d) s[threadIdx.x] += s[threadIdx.x + d];
        __syncthreads();
    }
    if (threadIdx.x == 0) bsum[blockIdx.x] = s[0];
}

// ---- scan step 2: exclusive scan of block sums (one block, 512 threads) ----
__global__ void k_scan2(const int* __restrict__ bsum, int* __restrict__ boff) {
    __shared__ int s[512];
    int t = threadIdx.x;
    int v = (t < NBLK) ? bsum[t] : 0;
    s[t] = v;
    __syncthreads();
    for (int d = 1; d < 512; d <<= 1) {
        int x = (t >= d) ? s[t - d] : 0;
        __syncthreads();
        s[t] += x;
        __syncthreads();
    }
    if (t < NBLK) boff[t] = s[t] - v;
}

// ---- scan step 3: off[i] (exclusive) = boff[blk] + local exclusive; cursor copy ----
__global__ void k_scan3(const int* __restrict__ degi, const int* __restrict__ boff,
                        int* __restrict__ off, int* __restrict__ cursor) {
    __shared__ int s[256];
    int t = threadIdx.x;
    int i = blockIdx.x * 256 + t;
    int v = (i < NN) ? degi[i] : 0;
    s[t] = v;
    __syncthreads();
    for (int d = 1; d < 256; d <<= 1) {
        int x = (t >= d) ? s[t - d] : 0;
        __syncthreads();
        s[t] += x;
        __syncthreads();
    }
    if (i < NN) {
        int o = boff[blockIdx.x] + s[t] - v;
        off[i] = o;
        cursor[i] = o;
    }
    if (i == NN - 1) off[NN] = NE;
}

// ---- CSR fill: eidx[pos] = src, bucketed by dst ----
__global__ void k_fill(const int* __restrict__ src, const int* __restrict__ dst,
                       int* __restrict__ cursor, int* __restrict__ eidx) {
    int e = blockIdx.x * blockDim.x + threadIdx.x;
    if (e < NE) {
        int v = dst[e];
        int p = atomAddI(&cursor[v], 1);
        eidx[p] = src[e];
    }
}

// ---- fused GIN node update: gather + h = relu((x + agg/max(deg,1)) @ W + b) ----
// 32 nodes per block; 8 threads/node gather 128 feats; W in LDS; 4x4 register tile.
// FUSE_HG: skip writing h; accumulate per-graph sums into hg_sum (graph_ids sorted).
template <bool FUSE_HG>
__global__ __launch_bounds__(256, 2) void k_node(
    const float* __restrict__ xin, const int* __restrict__ off,
    const int* __restrict__ eidx, const float* __restrict__ W,
    const float* __restrict__ b, float* __restrict__ hout,
    const int* __restrict__ gid, float* __restrict__ hg_sum)
{
    __shared__ float Wl[FD * FD];   // 64 KB
    __shared__ float T[32 * FD];    // 16 KB
    const int tid = threadIdx.x;
    const int base = blockIdx.x * 32;

    // load W into LDS (4096 float4, 16 per thread)
    {
        const float4* Wv = reinterpret_cast<const float4*>(W);
        float4* Wlv = reinterpret_cast<float4*>(Wl);
        #pragma unroll
        for (int i = 0; i < 16; ++i)
            Wlv[i * 256 + tid] = Wv[i * 256 + tid];
    }

    // gather: 8 threads per node, each owns 16 features (4 float4)
    {
        const int g = tid >> 3;          // node within block 0..31
        const int l = tid & 7;           // feature lane 0..7
        const int v = base + g;
        const int e0 = off[v], e1 = off[v + 1];
        float4 a0 = {0,0,0,0}, a1 = {0,0,0,0}, a2 = {0,0,0,0}, a3 = {0,0,0,0};
        for (int e = e0; e < e1; ++e) {
            const float4* xs = reinterpret_cast<const float4*>(
                xin + (size_t)eidx[e] * FD) + l * 4;
            add4(a0, xs[0]); add4(a1, xs[1]); add4(a2, xs[2]); add4(a3, xs[3]);
        }
        const float inv = 1.0f / fmaxf((float)(e1 - e0), 1.0f);
        const float4* xv = reinterpret_cast<const float4*>(xin + (size_t)v * FD) + l * 4;
        float4* Tv = reinterpret_cast<float4*>(T + g * FD) + l * 4;
        Tv[0] = axpy4(a0, inv, xv[0]);
        Tv[1] = axpy4(a1, inv, xv[1]);
        Tv[2] = axpy4(a2, inv, xv[2]);
        Tv[3] = axpy4(a3, inv, xv[3]);
    }
    __syncthreads();

    // thread -> 4 features x 4 nodes
    const int fg = tid & 31;
    const int ng = tid >> 5;
    const int f0 = fg * 4;
    const int n0 = ng * 4;

    float4 bv = *reinterpret_cast<const float4*>(b + f0);
    float acc[4][4];
    #pragma unroll
    for (int n = 0; n < 4; ++n) {
        acc[n][0] = bv.x; acc[n][1] = bv.y; acc[n][2] = bv.z; acc[n][3] = bv.w;
    }

    #pragma unroll 4
    for (int k = 0; k < FD; k += 4) {
        float4 w0 = *reinterpret_cast<const float4*>(&Wl[(k + 0) * FD + f0]);
        float4 w1 = *reinterpret_cast<const float4*>(&Wl[(k + 1) * FD + f0]);
        float4 w2 = *reinterpret_cast<const float4*>(&Wl[(k + 2) * FD + f0]);
        float4 w3 = *reinterpret_cast<const float4*>(&Wl[(k + 3) * FD + f0]);
        #pragma unroll
        for (int n = 0; n < 4; ++n) {
            float4 tv = *reinterpret_cast<const float4*>(&T[(n0 + n) * FD + k]);
            acc[n][0] += tv.x * w0.x + tv.y * w1.x + tv.z * w2.x + tv.w * w3.x;
            acc[n][1] += tv.x * w0.y + tv.y * w1.y + tv.z * w2.y + tv.w * w3.y;
            acc[n][2] += tv.x * w0.z + tv.y * w1.z + tv.z * w2.z + tv.w * w3.z;
            acc[n][3] += tv.x * w0.w + tv.y * w1.w + tv.z * w2.w + tv.w * w3.w;
        }
    }

    if (!FUSE_HG) {
        #pragma unroll
        for (int n = 0; n < 4; ++n) {
            float4 o;
            o.x = fmaxf(acc[n][0], 0.0f);
            o.y = fmaxf(acc[n][1], 0.0f);
            o.z = fmaxf(acc[n][2], 0.0f);
            o.w = fmaxf(acc[n][3], 0.0f);
            *reinterpret_cast<float4*>(hout + (size_t)(base + n0 + n) * FD + f0) = o;
        }
    } else {
        int curg = gid[base + n0];
        float r0 = 0.f, r1 = 0.f, r2 = 0.f, r3 = 0.f;
        #pragma unroll
        for (int n = 0; n < 4; ++n) {
            int g = gid[base + n0 + n];
            if (g != curg) {
                float* hp = hg_sum + (size_t)curg * FD + f0;
                atomAddF(hp + 0, r0); atomAddF(hp + 1, r1);
                atomAddF(hp + 2, r2); atomAddF(hp + 3, r3);
                r0 = r1 = r2 = r3 = 0.f;
                curg = g;
            }
            r0 += fmaxf(acc[n][0], 0.0f);
            r1 += fmaxf(acc[n][1], 0.0f);
            r2 += fmaxf(acc[n][2], 0.0f);
            r3 += fmaxf(acc[n][3], 0.0f);
        }
        float* hp = hg_sum + (size_t)curg * FD + f0;
        atomAddF(hp + 0, r0); atomAddF(hp + 1, r1);
        atomAddF(hp + 2, r2); atomAddF(hp + 3, r3);
    }
}

// ---- hg = hg_sum / max(count,1) -> d_out[0:8192] ----
__global__ void k_hg(const float* __restrict__ hg_sum, const float* __restrict__ gcount,
                     float* __restrict__ out) {
    int i = blockIdx.x * blockDim.x + threadIdx.x;
    int g = i >> 7;
    out[i] = hg_sum[i] / fmaxf(gcount[g], 1.0f);
}

// ---- t1 = relu(hg @ Wd1 + bd1) ----
__global__ void k_rec1(const float* __restrict__ hg, const float* __restrict__ Wd1,
                       const float* __restrict__ bd1, float* __restrict__ t1) {
    int i = blockIdx.x * blockDim.x + threadIdx.x;
    int n = i >> 7, f = i & 127;
    float acc = bd1[f];
    #pragma unroll 8
    for (int k = 0; k < FD; ++k)
        acc += hg[n * FD + k] * Wd1[k * FD + f];
    t1[i] = fmaxf(acc, 0.0f);
}

// ---- rec = t1 @ Wd2 + bd2 -> d_out[8192:12288] ----
__global__ void k_rec2(const float* __restrict__ t1, const float* __restrict__ Wd2,
                       const float* __restrict__ bd2, float* __restrict__ out) {
    int i = blockIdx.x * blockDim.x + threadIdx.x;
    int n = i >> 6, f = i & 63;
    float acc = bd2[f];
    #pragma unroll 8
    for (int k = 0; k < FD; ++k)
        acc += t1[n * FD + k] * Wd2[k * OUTD + f];
    out[i] = acc;
}

extern "C" void kernel_launch(void* const* d_in, const int* in_sizes, int n_in,
                              void* d_out, int out_size, void* d_ws, size_t ws_size,
                              hipStream_t stream) {
    const float* feat = (const float*)d_in[0];
    const int*   src  = (const int*)d_in[1];
    const int*   dst  = (const int*)d_in[2];
    const int*   gid  = (const int*)d_in[3];
    const float* W1   = (const float*)d_in[4];
    const float* b1   = (const float*)d_in[5];
    const float* W2   = (const float*)d_in[6];
    const float* b2   = (const float*)d_in[7];
    const float* Wd1  = (const float*)d_in[8];
    const float* bd1  = (const float*)d_in[9];
    const float* Wd2  = (const float*)d_in[10];
    const float* bd2  = (const float*)d_in[11];
    float* out = (float*)d_out;

    // workspace layout (4-byte units)
    char* wsb = (char*)d_ws;
    int*   degi   = (int*)wsb;                         // [100000]
    float* gcount = (float*)(wsb + 100000 * 4);        // [64]
    float* hg_sum = (float*)(wsb + 100064 * 4);        // [8192]
    int*   off    = (int*)(wsb + 108256 * 4);          // [100001]
    int*   cursor = (int*)(wsb + 208260 * 4);          // [100000]
    int*   bsum   = (int*)(wsb + 308260 * 4);          // [512]
    int*   boff   = (int*)(wsb + 308772 * 4);          // [512]
    int*   eidx   = (int*)(wsb + 309284 * 4);          // [1600000]
    float* h1     = (float*)(wsb + 1909284ll * 4);     // [12800000] (16B aligned)
    float* t1     = (float*)(wsb + 14709284ll * 4);    // [8192]

    // zero degi + gcount + hg_sum (contiguous prefix)
    hipMemsetAsync(d_ws, 0, (size_t)108256 * 4, stream);

    // CSR build (once; reused by both layers)
    k_hist <<<(NE + 255) / 256, 256, 0, stream>>>(dst, degi);
    k_gcount<<<(NN + 255) / 256, 256, 0, stream>>>(gid, gcount);
    k_scan1<<<NBLK, 256, 0, stream>>>(degi, bsum);
    k_scan2<<<1, 512, 0, stream>>>(bsum, boff);
    k_scan3<<<NBLK, 256, 0, stream>>>(degi, boff, off, cursor);
    k_fill <<<(NE + 255) / 256, 256, 0, stream>>>(src, dst, cursor, eidx);

    // layer 1 (fused gather + matmul)
    k_node<false><<<NN / 32, 256, 0, stream>>>(feat, off, eidx, W1, b1, h1, nullptr, nullptr);
    // layer 2 (fused gather + matmul + per-graph sum)
    k_node<true><<<NN / 32, 256, 0, stream>>>(h1, off, eidx, W2, b2, nullptr, gid, hg_sum);

    // pool + decoder
    k_hg  <<<32, 256, 0, stream>>>(hg_sum, gcount, out);
    k_rec1<<<32, 256, 0, stream>>>(out, Wd1, bd1, t1);
    k_rec2<<<16, 256, 0, stream>>>(t1, Wd2, bd2, out + 8192);
}

// Round 3
// 713.685 us; speedup vs baseline: 7.9006x; 1.2466x over previous
//
#include <hip/hip_runtime.h>

#define NN 100000
#define NE 1600000
#define FD 128
#define NG 64
#define OUTD 64
#define NBLK 391   // ceil(NN/256)

static __device__ __forceinline__ void atomAddF(float* p, float v) {
    __hip_atomic_fetch_add(p, v, __ATOMIC_RELAXED, __HIP_MEMORY_SCOPE_AGENT);
}
static __device__ __forceinline__ int atomAddI(int* p, int v) {
    return __hip_atomic_fetch_add(p, v, __ATOMIC_RELAXED, __HIP_MEMORY_SCOPE_AGENT);
}
static __device__ __forceinline__ void add4(float4& a, const float4 b) {
    a.x += b.x; a.y += b.y; a.z += b.z; a.w += b.w;
}
static __device__ __forceinline__ float4 axpy4(const float4 a, float s, const float4 x) {
    float4 r;
    r.x = x.x + a.x * s; r.y = x.y + a.y * s;
    r.z = x.z + a.z * s; r.w = x.w + a.w * s;
    return r;
}

// ---- int degree histogram over dst ----
__global__ void k_hist(const int* __restrict__ dst, int* __restrict__ degi) {
    int i = blockIdx.x * blockDim.x + threadIdx.x;
    if (i < NE) atomAddI(&degi[dst[i]], 1);
}

// ---- per-graph node counts (graph_ids sorted; LDS pre-reduce) ----
__global__ void k_gcount(const int* __restrict__ gid, float* __restrict__ gcount) {
    __shared__ float c[NG];
    if (threadIdx.x < NG) c[threadIdx.x] = 0.0f;
    __syncthreads();
    int i = blockIdx.x * blockDim.x + threadIdx.x;
    if (i < NN) atomicAdd(&c[gid[i]], 1.0f);
    __syncthreads();
    if (threadIdx.x < NG) {
        float v = c[threadIdx.x];
        if (v != 0.0f) atomAddF(&gcount[threadIdx.x], v);
    }
}

// ---- scan step 1: per-block sums of degi ----
__global__ void k_scan1(const int* __restrict__ degi, int* __restrict__ bsum) {
    __shared__ int s[256];
    int i = blockIdx.x * 256 + threadIdx.x;
    s[threadIdx.x] = (i < NN) ? degi[i] : 0;
    __syncthreads();
    for (int d = 128; d > 0; d >>= 1) {
        if (threadIdx.x < d) s[threadIdx.x] += s[threadIdx.x + d];
        __syncthreads();
    }
    if (threadIdx.x == 0) bsum[blockIdx.x] = s[0];
}

// ---- scan step 2: exclusive scan of block sums (one block, 512 threads) ----
__global__ void k_scan2(const int* __restrict__ bsum, int* __restrict__ boff) {
    __shared__ int s[512];
    int t = threadIdx.x;
    int v = (t < NBLK) ? bsum[t] : 0;
    s[t] = v;
    __syncthreads();
    for (int d = 1; d < 512; d <<= 1) {
        int x = (t >= d) ? s[t - d] : 0;
        __syncthreads();
        s[t] += x;
        __syncthreads();
    }
    if (t < NBLK) boff[t] = s[t] - v;
}

// ---- scan step 3: off[i] (exclusive) = boff[blk] + local exclusive; cursor copy ----
// NOTE: cursor may alias degi (each thread reads degi[i] before writing cursor[i]).
__global__ void k_scan3(const int* __restrict__ degi, const int* __restrict__ boff,
                        int* __restrict__ off, int* __restrict__ cursor) {
    __shared__ int s[256];
    int t = threadIdx.x;
    int i = blockIdx.x * 256 + t;
    int v = (i < NN) ? degi[i] : 0;
    s[t] = v;
    __syncthreads();
    for (int d = 1; d < 256; d <<= 1) {
        int x = (t >= d) ? s[t - d] : 0;
        __syncthreads();
        s[t] += x;
        __syncthreads();
    }
    if (i < NN) {
        int o = boff[blockIdx.x] + s[t] - v;
        off[i] = o;
        cursor[i] = o;
    }
    if (i == NN - 1) off[NN] = NE;
}

// ---- CSR fill: eidx[pos] = src, bucketed by dst ----
__global__ void k_fill(const int* __restrict__ src, const int* __restrict__ dst,
                       int* __restrict__ cursor, int* __restrict__ eidx) {
    int e = blockIdx.x * blockDim.x + threadIdx.x;
    if (e < NE) {
        int v = dst[e];
        int p = atomAddI(&cursor[v], 1);
        eidx[p] = src[e];
    }
}

// ---- gather: T[v] = x[v] + (sum_{u->v} x[u]) / max(deg,1) ----
// 32 threads per node, 1 float4 per thread, 4-edge unroll for MLP.
// No LDS, low VGPR -> high occupancy; this is the latency-hiding kernel.
__global__ __launch_bounds__(256) void k_gather(
    const float* __restrict__ x, const int* __restrict__ off,
    const int* __restrict__ eidx, float* __restrict__ T)
{
    const int t = blockIdx.x * 256 + threadIdx.x;   // grid exact: NN*32 threads
    const int v = t >> 5;
    const int l = t & 31;
    const int e0 = off[v], e1 = off[v + 1];
    float4 a = {0.f, 0.f, 0.f, 0.f};
    int e = e0;
    for (; e + 4 <= e1; e += 4) {
        int s0 = eidx[e + 0], s1 = eidx[e + 1];
        int s2 = eidx[e + 2], s3 = eidx[e + 3];
        float4 v0 = *(reinterpret_cast<const float4*>(x + (size_t)s0 * FD) + l);
        float4 v1 = *(reinterpret_cast<const float4*>(x + (size_t)s1 * FD) + l);
        float4 v2 = *(reinterpret_cast<const float4*>(x + (size_t)s2 * FD) + l);
        float4 v3 = *(reinterpret_cast<const float4*>(x + (size_t)s3 * FD) + l);
        add4(a, v0); add4(a, v1); add4(a, v2); add4(a, v3);
    }
    for (; e < e1; ++e)
        add4(a, *(reinterpret_cast<const float4*>(x + (size_t)eidx[e] * FD) + l));
    const float inv = 1.0f / fmaxf((float)(e1 - e0), 1.0f);
    float4 xv = *(reinterpret_cast<const float4*>(x + (size_t)v * FD) + l);
    *(reinterpret_cast<float4*>(T + (size_t)v * FD) + l) = axpy4(a, inv, xv);
}

// ---- dense GEMM: h = relu(T @ W + b) ; 32 nodes/block, W+tile in LDS ----
// FUSE_HG: skip writing h; accumulate per-graph sums into hg_sum (graph_ids sorted).
template <bool FUSE_HG>
__global__ __launch_bounds__(256, 2) void k_mm(
    const float* __restrict__ Tin, const float* __restrict__ W,
    const float* __restrict__ b, float* __restrict__ hout,
    const int* __restrict__ gid, float* __restrict__ hg_sum)
{
    __shared__ float Wl[FD * FD];   // 64 KB
    __shared__ float Ts[32 * FD];   // 16 KB
    const int tid = threadIdx.x;
    const int base = blockIdx.x * 32;

    // load W into LDS (4096 float4, 16 per thread)
    {
        const float4* Wv = reinterpret_cast<const float4*>(W);
        float4* Wlv = reinterpret_cast<float4*>(Wl);
        #pragma unroll
        for (int i = 0; i < 16; ++i)
            Wlv[i * 256 + tid] = Wv[i * 256 + tid];
    }
    // stage T tile (1024 float4, 4 per thread, coalesced)
    {
        const float4* Tg = reinterpret_cast<const float4*>(Tin + (size_t)base * FD);
        float4* Tv = reinterpret_cast<float4*>(Ts);
        #pragma unroll
        for (int i = 0; i < 4; ++i)
            Tv[i * 256 + tid] = Tg[i * 256 + tid];
    }
    __syncthreads();

    // thread -> 4 features x 4 nodes
    const int fg = tid & 31;
    const int ng = tid >> 5;
    const int f0 = fg * 4;
    const int n0 = ng * 4;

    float4 bv = *reinterpret_cast<const float4*>(b + f0);
    float acc[4][4];
    #pragma unroll
    for (int n = 0; n < 4; ++n) {
        acc[n][0] = bv.x; acc[n][1] = bv.y; acc[n][2] = bv.z; acc[n][3] = bv.w;
    }

    #pragma unroll 4
    for (int k = 0; k < FD; k += 4) {
        float4 w0 = *reinterpret_cast<const float4*>(&Wl[(k + 0) * FD + f0]);
        float4 w1 = *reinterpret_cast<const float4*>(&Wl[(k + 1) * FD + f0]);
        float4 w2 = *reinterpret_cast<const float4*>(&Wl[(k + 2) * FD + f0]);
        float4 w3 = *reinterpret_cast<const float4*>(&Wl[(k + 3) * FD + f0]);
        #pragma unroll
        for (int n = 0; n < 4; ++n) {
            float4 tv = *reinterpret_cast<const float4*>(&Ts[(n0 + n) * FD + k]);
            acc[n][0] += tv.x * w0.x + tv.y * w1.x + tv.z * w2.x + tv.w * w3.x;
            acc[n][1] += tv.x * w0.y + tv.y * w1.y + tv.z * w2.y + tv.w * w3.y;
            acc[n][2] += tv.x * w0.z + tv.y * w1.z + tv.z * w2.z + tv.w * w3.z;
            acc[n][3] += tv.x * w0.w + tv.y * w1.w + tv.z * w2.w + tv.w * w3.w;
        }
    }

    if (!FUSE_HG) {
        #pragma unroll
        for (int n = 0; n < 4; ++n) {
            float4 o;
            o.x = fmaxf(acc[n][0], 0.0f);
            o.y = fmaxf(acc[n][1], 0.0f);
            o.z = fmaxf(acc[n][2], 0.0f);
            o.w = fmaxf(acc[n][3], 0.0f);
            *reinterpret_cast<float4*>(hout + (size_t)(base + n0 + n) * FD + f0) = o;
        }
    } else {
        int curg = gid[base + n0];
        float r0 = 0.f, r1 = 0.f, r2 = 0.f, r3 = 0.f;
        #pragma unroll
        for (int n = 0; n < 4; ++n) {
            int g = gid[base + n0 + n];
            if (g != curg) {
                float* hp = hg_sum + (size_t)curg * FD + f0;
                atomAddF(hp + 0, r0); atomAddF(hp + 1, r1);
                atomAddF(hp + 2, r2); atomAddF(hp + 3, r3);
                r0 = r1 = r2 = r3 = 0.f;
                curg = g;
            }
            r0 += fmaxf(acc[n][0], 0.0f);
            r1 += fmaxf(acc[n][1], 0.0f);
            r2 += fmaxf(acc[n][2], 0.0f);
            r3 += fmaxf(acc[n][3], 0.0f);
        }
        float* hp = hg_sum + (size_t)curg * FD + f0;
        atomAddF(hp + 0, r0); atomAddF(hp + 1, r1);
        atomAddF(hp + 2, r2); atomAddF(hp + 3, r3);
    }
}

// ---- hg = hg_sum / max(count,1) -> d_out[0:8192] ----
__global__ void k_hg(const float* __restrict__ hg_sum, const float* __restrict__ gcount,
                     float* __restrict__ out) {
    int i = blockIdx.x * blockDim.x + threadIdx.x;
    int g = i >> 7;
    out[i] = hg_sum[i] / fmaxf(gcount[g], 1.0f);
}

// ---- t1 = relu(hg @ Wd1 + bd1) ----
__global__ void k_rec1(const float* __restrict__ hg, const float* __restrict__ Wd1,
                       const float* __restrict__ bd1, float* __restrict__ t1) {
    int i = blockIdx.x * blockDim.x + threadIdx.x;
    int n = i >> 7, f = i & 127;
    float acc = bd1[f];
    #pragma unroll 8
    for (int k = 0; k < FD; ++k)
        acc += hg[n * FD + k] * Wd1[k * FD + f];
    t1[i] = fmaxf(acc, 0.0f);
}

// ---- rec = t1 @ Wd2 + bd2 -> d_out[8192:12288] ----
__global__ void k_rec2(const float* __restrict__ t1, const float* __restrict__ Wd2,
                       const float* __restrict__ bd2, float* __restrict__ out) {
    int i = blockIdx.x * blockDim.x + threadIdx.x;
    int n = i >> 6, f = i & 63;
    float acc = bd2[f];
    #pragma unroll 8
    for (int k = 0; k < FD; ++k)
        acc += t1[n * FD + k] * Wd2[k * OUTD + f];
    out[i] = acc;
}

extern "C" void kernel_launch(void* const* d_in, const int* in_sizes, int n_in,
                              void* d_out, int out_size, void* d_ws, size_t ws_size,
                              hipStream_t stream) {
    const float* feat = (const float*)d_in[0];
    const int*   src  = (const int*)d_in[1];
    const int*   dst  = (const int*)d_in[2];
    const int*   gid  = (const int*)d_in[3];
    const float* W1   = (const float*)d_in[4];
    const float* b1   = (const float*)d_in[5];
    const float* W2   = (const float*)d_in[6];
    const float* b2   = (const float*)d_in[7];
    const float* Wd1  = (const float*)d_in[8];
    const float* bd1  = (const float*)d_in[9];
    const float* Wd2  = (const float*)d_in[10];
    const float* bd2  = (const float*)d_in[11];
    float* out = (float*)d_out;

    // workspace layout (4-byte units)
    char* wsb = (char*)d_ws;
    int*   degi   = (int*)wsb;                          // [100000] (reused as cursor)
    float* gcount = (float*)(wsb + 100000ll * 4);       // [64]
    float* hg_sum = (float*)(wsb + 100064ll * 4);       // [8192]
    int*   off    = (int*)(wsb + 108256ll * 4);         // [100001]
    int*   bsum   = (int*)(wsb + 208260ll * 4);         // [512]
    int*   boff   = (int*)(wsb + 208772ll * 4);         // [512]
    int*   eidx   = (int*)(wsb + 209284ll * 4);         // [1600000]
    float* T      = (float*)(wsb + 1809284ll * 4);      // [12800000] (16B aligned)
    float* h1     = (float*)(wsb + 14609284ll * 4);     // [12800000] (16B aligned)
    float* t1     = (float*)(wsb + 27409284ll * 4);     // [8192]
    int*   cursor = degi;                               // alias: degi dead after scan3

    // zero degi + gcount + hg_sum (contiguous prefix)
    hipMemsetAsync(d_ws, 0, (size_t)108256 * 4, stream);

    // CSR build (once; reused by both layers)
    k_hist <<<(NE + 255) / 256, 256, 0, stream>>>(dst, degi);
    k_gcount<<<(NN + 255) / 256, 256, 0, stream>>>(gid, gcount);
    k_scan1<<<NBLK, 256, 0, stream>>>(degi, bsum);
    k_scan2<<<1, 512, 0, stream>>>(bsum, boff);
    k_scan3<<<NBLK, 256, 0, stream>>>(degi, boff, off, cursor);
    k_fill <<<(NE + 255) / 256, 256, 0, stream>>>(src, dst, cursor, eidx);

    // layer 1: gather (high-occupancy) then dense GEMM
    k_gather<<<NN * 32 / 256, 256, 0, stream>>>(feat, off, eidx, T);
    k_mm<false><<<NN / 32, 256, 0, stream>>>(T, W1, b1, h1, nullptr, nullptr);

    // layer 2: gather from h1, GEMM + fused per-graph sum
    k_gather<<<NN * 32 / 256, 256, 0, stream>>>(h1, off, eidx, T);
    k_mm<true><<<NN / 32, 256, 0, stream>>>(T, W2, b2, nullptr, gid, hg_sum);

    // pool + decoder
    k_hg  <<<32, 256, 0, stream>>>(hg_sum, gcount, out);
    k_rec1<<<32, 256, 0, stream>>>(out, Wd1, bd1, t1);
    k_rec2<<<16, 256, 0, stream>>>(t1, Wd2, bd2, out + 8192);
}

// Round 4
// 476.479 us; speedup vs baseline: 11.8338x; 1.4978x over previous
//
#include <hip/hip_runtime.h>

#define NN 100000
#define NE 1600000
#define FD 128
#define NG 64
#define OUTD 64
#define NBLK 391   // ceil(NN/256)

typedef __attribute__((ext_vector_type(8))) short bf16x8;
typedef __attribute__((ext_vector_type(4))) float f32x4;
typedef __attribute__((ext_vector_type(8))) unsigned short u16x8;

static __device__ __forceinline__ void atomAddF(float* p, float v) {
    __hip_atomic_fetch_add(p, v, __ATOMIC_RELAXED, __HIP_MEMORY_SCOPE_AGENT);
}
static __device__ __forceinline__ int atomAddI(int* p, int v) {
    return __hip_atomic_fetch_add(p, v, __ATOMIC_RELAXED, __HIP_MEMORY_SCOPE_AGENT);
}
// fp32 -> bf16 round-to-nearest-even
static __device__ __forceinline__ unsigned short f2bf(float f) {
    unsigned int u = __float_as_uint(f);
    u += 0x7FFFu + ((u >> 16) & 1u);
    return (unsigned short)(u >> 16);
}
static __device__ __forceinline__ float bf2f(unsigned short h) {
    return __uint_as_float(((unsigned int)h) << 16);
}

// ================= CSR build =================
__global__ void k_hist(const int* __restrict__ dst, int* __restrict__ degi) {
    int i = blockIdx.x * blockDim.x + threadIdx.x;
    if (i < NE) atomAddI(&degi[dst[i]], 1);
}

__global__ void k_gcount(const int* __restrict__ gid, float* __restrict__ gcount) {
    __shared__ float c[NG];
    if (threadIdx.x < NG) c[threadIdx.x] = 0.0f;
    __syncthreads();
    int i = blockIdx.x * blockDim.x + threadIdx.x;
    if (i < NN) atomicAdd(&c[gid[i]], 1.0f);
    __syncthreads();
    if (threadIdx.x < NG) {
        float v = c[threadIdx.x];
        if (v != 0.0f) atomAddF(&gcount[threadIdx.x], v);
    }
}

__global__ void k_scan1(const int* __restrict__ degi, int* __restrict__ bsum) {
    __shared__ int s[256];
    int i = blockIdx.x * 256 + threadIdx.x;
    s[threadIdx.x] = (i < NN) ? degi[i] : 0;
    __syncthreads();
    for (int d = 128; d > 0; d >>= 1) {
        if (threadIdx.x < d) s[threadIdx.x] += s[threadIdx.x + d];
        __syncthreads();
    }
    if (threadIdx.x == 0) bsum[blockIdx.x] = s[0];
}

__global__ void k_scan2(const int* __restrict__ bsum, int* __restrict__ boff) {
    __shared__ int s[512];
    int t = threadIdx.x;
    int v = (t < NBLK) ? bsum[t] : 0;
    s[t] = v;
    __syncthreads();
    for (int d = 1; d < 512; d <<= 1) {
        int x = (t >= d) ? s[t - d] : 0;
        __syncthreads();
        s[t] += x;
        __syncthreads();
    }
    if (t < NBLK) boff[t] = s[t] - v;
}

__global__ void k_scan3(const int* __restrict__ degi, const int* __restrict__ boff,
                        int* __restrict__ off, int* __restrict__ cursor) {
    __shared__ int s[256];
    int t = threadIdx.x;
    int i = blockIdx.x * 256 + t;
    int v = (i < NN) ? degi[i] : 0;
    s[t] = v;
    __syncthreads();
    for (int d = 1; d < 256; d <<= 1) {
        int x = (t >= d) ? s[t - d] : 0;
        __syncthreads();
        s[t] += x;
        __syncthreads();
    }
    if (i < NN) {
        int o = boff[blockIdx.x] + s[t] - v;
        off[i] = o;
        cursor[i] = o;
    }
    if (i == NN - 1) off[NN] = NE;
}

__global__ void k_fill(const int* __restrict__ src, const int* __restrict__ dst,
                       int* __restrict__ cursor, int* __restrict__ eidx) {
    int e = blockIdx.x * blockDim.x + threadIdx.x;
    if (e < NE) {
        int v = dst[e];
        int p = atomAddI(&cursor[v], 1);
        eidx[p] = src[e];
    }
}

// ================= W transpose + bf16 convert (Wt[n][k]) =================
__global__ void k_wt(const float* __restrict__ W1, const float* __restrict__ W2,
                     unsigned short* __restrict__ W1t, unsigned short* __restrict__ W2t) {
    int idx = blockIdx.x * 256 + threadIdx.x;      // 0..32767
    const float* W = (idx < 16384) ? W1 : W2;
    unsigned short* Wt = (idx < 16384) ? W1t : W2t;
    int i = idx & 16383;
    int k = i >> 7, n = i & 127;
    Wt[n * 128 + k] = f2bf(W[i]);
}

// ================= MFMA GEMM: Y = A @ W (bf16 in LDS, fp32 acc, bf16 out) ====
// Block: 64 nodes x 128 feats, 4 waves; wave w owns rows 16w..16w+15.
// LDS XOR-swizzle (T2): byte ^= (row&7)<<4 breaks the 16-way column-slice conflict.
template <bool A_FP32>
__global__ __launch_bounds__(256) void k_gemm(
    const void* __restrict__ Ain, const unsigned short* __restrict__ Wt,
    unsigned short* __restrict__ Y)
{
    __shared__ unsigned short As[64 * 128];    // 16 KB, swizzled rows of 256B
    __shared__ unsigned short Bs[128 * 128];   // 32 KB, Wt rows (n-major), swizzled
    const int tid = threadIdx.x;
    const int base = blockIdx.x * 64;
    char* AsB = reinterpret_cast<char*>(As);
    char* BsB = reinterpret_cast<char*>(Bs);

    // stage B (Wt bf16 [128n][128k]): 128 rows x 16 x 16B slots
    {
        const u16x8* Wv = reinterpret_cast<const u16x8*>(Wt);
        #pragma unroll
        for (int i = 0; i < 8; ++i) {
            int idx = i * 256 + tid;             // 0..2047
            int n = idx >> 4, s = idx & 15;
            int soff = (s * 16) ^ ((n & 7) << 4);
            *reinterpret_cast<u16x8*>(BsB + n * 256 + soff) = Wv[idx];
        }
    }
    // stage A (64 rows x 128 k), convert fp32->bf16 if needed
    if (A_FP32) {
        const float4* Av = reinterpret_cast<const float4*>(Ain);
        #pragma unroll
        for (int i = 0; i < 8; ++i) {
            int idx = i * 256 + tid;             // 64 rows x 32 float4
            int r = idx >> 5, c4 = idx & 31;
            int row = base + r;
            float4 v;
            if (row < NN) v = Av[(size_t)row * 32 + c4];
            else { v.x = v.y = v.z = v.w = 0.0f; }
            unsigned short h[4] = { f2bf(v.x), f2bf(v.y), f2bf(v.z), f2bf(v.w) };
            int soff = (c4 * 8) ^ ((r & 7) << 4);
            *reinterpret_cast<uint2*>(AsB + r * 256 + soff) = *reinterpret_cast<uint2*>(h);
        }
    } else {
        const u16x8* Av = reinterpret_cast<const u16x8*>(Ain);
        #pragma unroll
        for (int i = 0; i < 4; ++i) {
            int idx = i * 256 + tid;             // 64 rows x 16 slots
            int r = idx >> 4, s = idx & 15;
            int row = base + r;
            u16x8 v;
            if (row < NN) v = Av[(size_t)row * 16 + s];
            else v = (u16x8){0,0,0,0,0,0,0,0};
            int soff = (s * 16) ^ ((r & 7) << 4);
            *reinterpret_cast<u16x8*>(AsB + r * 256 + soff) = v;
        }
    }
    __syncthreads();

    const int lane = tid & 63;
    const int w = tid >> 6;
    const int rowb = w * 16;
    const int r = rowb + (lane & 15);     // A row for this lane
    const int kb = lane >> 4;             // k sub-block 0..3 (8 elems each)
    const int n = lane & 15;              // col within 16-col tile

    // A fragments: a[kt] holds A[r][kt*32 + kb*8 .. +7]
    bf16x8 a[4];
    #pragma unroll
    for (int kt = 0; kt < 4; ++kt) {
        int boff = (kt * 64 + kb * 16) ^ ((r & 7) << 4);
        a[kt] = *reinterpret_cast<bf16x8*>(AsB + r * 256 + boff);
    }

    f32x4 acc[8];
    #pragma unroll
    for (int ct = 0; ct < 8; ++ct) acc[ct] = (f32x4){0.f, 0.f, 0.f, 0.f};

    #pragma unroll
    for (int ct = 0; ct < 8; ++ct) {
        int col = ct * 16 + n;
        #pragma unroll
        for (int kt = 0; kt < 4; ++kt) {
            int boff = (kt * 64 + kb * 16) ^ ((col & 7) << 4);
            bf16x8 b = *reinterpret_cast<bf16x8*>(BsB + col * 256 + boff);
            acc[ct] = __builtin_amdgcn_mfma_f32_16x16x32_bf16(a[kt], b, acc[ct], 0, 0, 0);
        }
    }

    // C/D layout: col = lane&15, row = (lane>>4)*4 + reg  (within 16x16 tile)
    const int rbase = base + rowb + (lane >> 4) * 4;
    #pragma unroll
    for (int reg = 0; reg < 4; ++reg) {
        int node = rbase + reg;
        if (node < NN) {
            #pragma unroll
            for (int ct = 0; ct < 8; ++ct)
                Y[(size_t)node * FD + ct * 16 + n] = f2bf(acc[ct][reg]);
        }
    }
}

// ========= gather: H[v] = relu(Y[v] + mean_{u->v} Y[u] + bias) (bf16 I/O) =====
// 8 threads/node x 16 feats; POOL: accumulate per-graph sums (gid sorted) via LDS.
template <bool POOL>
__global__ __launch_bounds__(256) void k_agg(
    const unsigned short* __restrict__ Y, const int* __restrict__ off,
    const int* __restrict__ eidx, const float* __restrict__ bias,
    unsigned short* __restrict__ H,
    const int* __restrict__ gid, float* __restrict__ hg_sum)
{
    __shared__ float hl[FD];
    int gid0 = 0;
    if (POOL) {
        if (threadIdx.x < FD) hl[threadIdx.x] = 0.0f;
        gid0 = gid[blockIdx.x * 32];
        __syncthreads();
    }
    const int t = blockIdx.x * 256 + threadIdx.x;
    const int v = t >> 3;
    const int l = t & 7;
    const int fo = l * 16;
    const int e0 = off[v], e1 = off[v + 1];

    float a[16];
    #pragma unroll
    for (int j = 0; j < 16; ++j) a[j] = 0.0f;

    const u16x8* Yv = reinterpret_cast<const u16x8*>(Y);
    int e = e0;
    for (; e + 2 <= e1; e += 2) {
        int s0 = eidx[e], s1 = eidx[e + 1];
        u16x8 p0 = Yv[(size_t)s0 * 16 + l * 2];
        u16x8 p1 = Yv[(size_t)s0 * 16 + l * 2 + 1];
        u16x8 q0 = Yv[(size_t)s1 * 16 + l * 2];
        u16x8 q1 = Yv[(size_t)s1 * 16 + l * 2 + 1];
        #pragma unroll
        for (int j = 0; j < 8; ++j) {
            a[j]     += bf2f(p0[j]) + bf2f(q0[j]);
            a[8 + j] += bf2f(p1[j]) + bf2f(q1[j]);
        }
    }
    if (e < e1) {
        int s0 = eidx[e];
        u16x8 p0 = Yv[(size_t)s0 * 16 + l * 2];
        u16x8 p1 = Yv[(size_t)s0 * 16 + l * 2 + 1];
        #pragma unroll
        for (int j = 0; j < 8; ++j) { a[j] += bf2f(p0[j]); a[8 + j] += bf2f(p1[j]); }
    }

    const float inv = 1.0f / fmaxf((float)(e1 - e0), 1.0f);
    u16x8 sv0 = Yv[(size_t)v * 16 + l * 2];
    u16x8 sv1 = Yv[(size_t)v * 16 + l * 2 + 1];
    const float4* bvp = reinterpret_cast<const float4*>(bias + fo);
    float4 bq[4] = { bvp[0], bvp[1], bvp[2], bvp[3] };
    const float* bb = reinterpret_cast<const float*>(bq);

    float hv[16];
    #pragma unroll
    for (int j = 0; j < 8; ++j) {
        hv[j]     = fmaxf(bf2f(sv0[j]) + a[j] * inv + bb[j], 0.0f);
        hv[8 + j] = fmaxf(bf2f(sv1[j]) + a[8 + j] * inv + bb[8 + j], 0.0f);
    }

    if (!POOL) {
        u16x8 o0, o1;
        #pragma unroll
        for (int j = 0; j < 8; ++j) { o0[j] = f2bf(hv[j]); o1[j] = f2bf(hv[8 + j]); }
        u16x8* Hv = reinterpret_cast<u16x8*>(H);
        Hv[(size_t)v * 16 + l * 2]     = o0;
        Hv[(size_t)v * 16 + l * 2 + 1] = o1;
    } else {
        int g = gid[v];
        if (g == gid0) {
            #pragma unroll
            for (int j = 0; j < 16; ++j) atomicAdd(&hl[fo + j], hv[j]);
        } else {
            #pragma unroll
            for (int j = 0; j < 16; ++j) atomAddF(&hg_sum[(size_t)g * FD + fo + j], hv[j]);
        }
        __syncthreads();
        if (threadIdx.x < FD) {
            float x = hl[threadIdx.x];
            atomAddF(&hg_sum[(size_t)gid0 * FD + threadIdx.x], x);
        }
    }
}

// ================= pool divide + decoder =================
__global__ void k_hg(const float* __restrict__ hg_sum, const float* __restrict__ gcount,
                     float* __restrict__ out) {
    int i = blockIdx.x * blockDim.x + threadIdx.x;
    int g = i >> 7;
    out[i] = hg_sum[i] / fmaxf(gcount[g], 1.0f);
}

__global__ void k_rec1(const float* __restrict__ hg, const float* __restrict__ Wd1,
                       const float* __restrict__ bd1, float* __restrict__ t1) {
    int i = blockIdx.x * blockDim.x + threadIdx.x;
    int n = i >> 7, f = i & 127;
    float acc = bd1[f];
    #pragma unroll 8
    for (int k = 0; k < FD; ++k)
        acc += hg[n * FD + k] * Wd1[k * FD + f];
    t1[i] = fmaxf(acc, 0.0f);
}

__global__ void k_rec2(const float* __restrict__ t1, const float* __restrict__ Wd2,
                       const float* __restrict__ bd2, float* __restrict__ out) {
    int i = blockIdx.x * blockDim.x + threadIdx.x;
    int n = i >> 6, f = i & 63;
    float acc = bd2[f];
    #pragma unroll 8
    for (int k = 0; k < FD; ++k)
        acc += t1[n * FD + k] * Wd2[k * OUTD + f];
    out[i] = acc;
}

extern "C" void kernel_launch(void* const* d_in, const int* in_sizes, int n_in,
                              void* d_out, int out_size, void* d_ws, size_t ws_size,
                              hipStream_t stream) {
    const float* feat = (const float*)d_in[0];
    const int*   src  = (const int*)d_in[1];
    const int*   dst  = (const int*)d_in[2];
    const int*   gid  = (const int*)d_in[3];
    const float* W1   = (const float*)d_in[4];
    const float* b1   = (const float*)d_in[5];
    const float* W2   = (const float*)d_in[6];
    const float* b2   = (const float*)d_in[7];
    const float* Wd1  = (const float*)d_in[8];
    const float* bd1  = (const float*)d_in[9];
    const float* Wd2  = (const float*)d_in[10];
    const float* bd2  = (const float*)d_in[11];
    float* out = (float*)d_out;

    // workspace layout (4-byte units; all 16B-aligned where vector-accessed)
    char* wsb = (char*)d_ws;
    int*   degi   = (int*)wsb;                              // [100000] (reused as cursor)
    float* gcount = (float*)(wsb + 100000ll * 4);           // [64]
    float* hg_sum = (float*)(wsb + 100064ll * 4);           // [8192]
    int*   off    = (int*)(wsb + 108256ll * 4);             // [100001]
    int*   bsum   = (int*)(wsb + 208260ll * 4);             // [512]
    int*   boff   = (int*)(wsb + 208772ll * 4);             // [512]
    int*   eidx   = (int*)(wsb + 209284ll * 4);             // [1600000]
    unsigned short* W1t = (unsigned short*)(wsb + 1809284ll * 4);  // bf16 [16384]
    unsigned short* W2t = (unsigned short*)(wsb + 1817476ll * 4);  // bf16 [16384]
    unsigned short* Yb  = (unsigned short*)(wsb + 1825668ll * 4);  // bf16 [12800000]
    unsigned short* H1  = (unsigned short*)(wsb + 8225668ll * 4);  // bf16 [12800000]
    float* t1     = (float*)(wsb + 14625668ll * 4);         // [8192]
    int*   cursor = degi;                                   // degi dead after scan3

    // zero degi + gcount + hg_sum (contiguous prefix)
    hipMemsetAsync(d_ws, 0, (size_t)108256 * 4, stream);

    // CSR build + weight prep
    k_hist <<<(NE + 255) / 256, 256, 0, stream>>>(dst, degi);
    k_gcount<<<(NN + 255) / 256, 256, 0, stream>>>(gid, gcount);
    k_scan1<<<NBLK, 256, 0, stream>>>(degi, bsum);
    k_scan2<<<1, 512, 0, stream>>>(bsum, boff);
    k_scan3<<<NBLK, 256, 0, stream>>>(degi, boff, off, cursor);
    k_fill <<<(NE + 255) / 256, 256, 0, stream>>>(src, dst, cursor, eidx);
    k_wt   <<<128, 256, 0, stream>>>(W1, W2, W1t, W2t);

    // layer 1: y1 = x @ W1 (MFMA), h1 = relu(y1 + agg(y1) + b1)
    k_gemm<true><<<(NN + 63) / 64, 256, 0, stream>>>(feat, W1t, Yb);
    k_agg<false><<<NN * 8 / 256, 256, 0, stream>>>(Yb, off, eidx, b1, H1, nullptr, nullptr);

    // layer 2: y2 = h1 @ W2 (MFMA), h2 = relu(y2 + agg(y2) + b2) fused into pool
    k_gemm<false><<<(NN + 63) / 64, 256, 0, stream>>>(H1, W2t, Yb);
    k_agg<true><<<NN * 8 / 256, 256, 0, stream>>>(Yb, off, eidx, b2, nullptr, gid, hg_sum);

    // pool divide + decoder
    k_hg  <<<32, 256, 0, stream>>>(hg_sum, gcount, out);
    k_rec1<<<32, 256, 0, stream>>>(out, Wd1, bd1, t1);
    k_rec2<<<16, 256, 0, stream>>>(t1, Wd2, bd2, out + 8192);
}